// Round 4
// baseline (121.481 us; speedup 1.0000x reference)
//
#include <hip/hip_runtime.h>
#include <hip/hip_bf16.h>

typedef __attribute__((ext_vector_type(8))) __bf16 bf16x8;
typedef __attribute__((ext_vector_type(4))) float f32x4;

#define BM 256
#define BN 256
#define BK 64
#define THREADS 512
#define BUF_BYTES 65536   // per K-tile: A-lo|A-hi|B-lo|B-hi, 16KB each
#define R_ALO 0
#define R_AHI 16384
#define R_BLO 32768
#define R_BHI 49152

#define VMCNT(n) asm volatile("s_waitcnt vmcnt(" #n ")" ::: "memory")
#define LGKM(n)  asm volatile("s_waitcnt lgkmcnt(" #n ")" ::: "memory")
#define MFMA16(a, b, c) __builtin_amdgcn_mfma_f32_16x16x32_bf16((a), (b), (c), 0, 0, 0)

static __device__ inline void gload_lds16(const void* g, void* l) {
  __builtin_amdgcn_global_load_lds((__attribute__((address_space(1))) void*)g,
                                   (__attribute__((address_space(3))) void*)l,
                                   16, 0, 0);
}

// ---------------- QDQ (merged x+w): per-256-group absmax, degenerate FP4 grid --------
// scale = max(absmax,1e-6); q in {0,+-0.5,+-1}; out = bf16(q*scale)
__global__ __launch_bounds__(256) void qdq2(const float* __restrict__ x,
                                            __hip_bfloat16* __restrict__ qx, int gx,
                                            const float* __restrict__ w,
                                            __hip_bfloat16* __restrict__ qw, int gtot) {
  int g = (blockIdx.x << 2) + (threadIdx.x >> 6);
  if (g >= gtot) return;
  const int lane = threadIdx.x & 63;
  const float* src = (g < gx) ? x : w;
  __hip_bfloat16* dst = (g < gx) ? qx : qw;
  const size_t base = (size_t)(g < gx ? g : g - gx) * 256 + (size_t)lane * 4;
  float4 v = *reinterpret_cast<const float4*>(src + base);
  float amax = fmaxf(fmaxf(fabsf(v.x), fabsf(v.y)), fmaxf(fabsf(v.z), fabsf(v.w)));
#pragma unroll
  for (int off = 32; off > 0; off >>= 1)
    amax = fmaxf(amax, __shfl_xor(amax, off, 64));
  float scale = fmaxf(amax, 1e-6f);
  float in[4] = {v.x, v.y, v.z, v.w};
  union { ushort4 u4; __hip_bfloat16 h[4]; } o;
#pragma unroll
  for (int i = 0; i < 4; ++i) {
    float t = fabsf(in[i] / scale);
    float q = t < 0.25f ? 0.0f : (t < 0.75f ? 0.5f : 1.0f);
    o.h[i] = __float2bfloat16(copysignf(q, in[i]) * scale);
  }
  *reinterpret_cast<ushort4*>(dst + base) = o.u4;
}

// ---------------- GEMM 256x256, 8 waves, 4-phase/K-tile pipelined schedule -----------
// LDS per half-region [128 rows][8 chunks of 16B]: byte = r*128 + (c^(r&7))*16.
// gload_lds dest is linear; global SOURCE is inverse-permuted; ds_read swizzled.
// Stage slots (iter t): ph0: A-hi(t+1) | ph2: B-lo(t+2) | ph3: A-lo(t+2)+B-hi(t+2).
// Each overwrites a region last read >=1 barrier earlier. One vmcnt per K-tile at ph3:
// tile t+1's last half staged at iter-t ph0; 3 halves (6 loads) issued after -> vmcnt(6).
__global__ __launch_bounds__(THREADS, 2) void gemm256(
    const __hip_bfloat16* __restrict__ A,  // [M,K]
    const __hip_bfloat16* __restrict__ B,  // [N,K]
    const float* __restrict__ bias,        // [N]
    float* __restrict__ C,                 // [M,N]
    int M, int N, int K) {
  extern __shared__ char smem[];

  const int tid = threadIdx.x;
  const int lane = tid & 63;
  const int wid = tid >> 6;
  const int wm = wid >> 2;   // A half (0=lo rows 0-127, 1=hi)
  const int wn = wid & 3;    // 64-col strip; B half = wn>>1
  const int fr = lane & 15;
  const int hi = lane >> 4;

  const int nwg = gridDim.x;
  int bid = blockIdx.x;
  if ((nwg & 7) == 0) bid = (bid & 7) * (nwg >> 3) + (bid >> 3);
  const int ntn = N / BN;
  const int tm = bid / ntn, tn = bid % ntn;
  const int m0 = tm * BM, n0 = tn * BN;

  // staging source map (inverse swizzle): thread tid, sub-load jj:
  // dest D = jj*8192 + tid*16 -> r = jj*64 + (tid>>3), cphys = tid&7,
  // c = cphys ^ (r&7) = (tid&7)^((tid>>3)&7)   (jj*64 drops mod 8)
  const int r_st = tid >> 3;
  const size_t c_st8 = (size_t)(((tid & 7) ^ ((tid >> 3) & 7)) << 3);
  const size_t src_off = (size_t)r_st * K + c_st8;
  const size_t k64 = (size_t)K * 64;
  const __hip_bfloat16* Alo_p = A + (size_t)m0 * K;
  const __hip_bfloat16* Ahi_p = A + (size_t)(m0 + 128) * K;
  const __hip_bfloat16* Blo_p = B + (size_t)n0 * K;
  const __hip_bfloat16* Bhi_p = B + (size_t)(n0 + 128) * K;
  const int d16 = tid * 16;

#define STAGE_HALF(bufi, regOff, gbase, tt) do {                        \
    char* bb = smem + (size_t)(bufi) * BUF_BYTES + (regOff);            \
    const __hip_bfloat16* gp = (gbase) + src_off + (size_t)(tt) * BK;   \
    gload_lds16(gp, bb + d16);                                          \
    gload_lds16(gp + k64, bb + 8192 + d16);                             \
  } while (0)

  // swizzled read offsets: frag (i|j, kk): r = (i*16|strip+j*16)+fr, chunk = kk*4+hi
  const int sw0 = ((hi ^ (fr & 7)) << 4);
  const int sw1 = (((4 + hi) ^ (fr & 7)) << 4);
  const int aB = wm * 16384 + fr * 128;                                  // + i*2048
  const int bB = R_BLO + (wn >> 1) * 16384 + (wn & 1) * 8192 + fr * 128; // + j*2048

  f32x4 acc[8][4];
#pragma unroll
  for (int i = 0; i < 8; ++i)
#pragma unroll
    for (int j = 0; j < 4; ++j) acc[i][j] = (f32x4){0.f, 0.f, 0.f, 0.f};

  const int T = K / BK;

  // prologue: tile0 fully, tile1 all but A-hi (A-hi(1) staged at iter0 ph0)
  STAGE_HALF(0, R_ALO, Alo_p, 0);
  STAGE_HALF(0, R_BLO, Blo_p, 0);
  STAGE_HALF(0, R_BHI, Bhi_p, 0);
  STAGE_HALF(0, R_AHI, Ahi_p, 0);
  if (T > 1) {
    STAGE_HALF(1, R_BLO, Blo_p, 1);
    STAGE_HALF(1, R_ALO, Alo_p, 1);
    STAGE_HALF(1, R_BHI, Bhi_p, 1);
    VMCNT(6);
  } else {
    VMCNT(0);
  }
  __builtin_amdgcn_s_barrier();

  for (int t = 0; t < T; ++t) {
    const char* ab = smem + (size_t)(t & 1) * BUF_BYTES;
    bf16x8 a[4][2], b0[2][2], b1[2][2];

    // ---- ph0: Q0 = a(i0-3) x b(j0-1) ----  12 ds_read + stage A-hi(t+1)
#pragma unroll
    for (int i = 0; i < 4; ++i) {
      a[i][0] = *(const bf16x8*)(ab + aB + i * 2048 + sw0);
      a[i][1] = *(const bf16x8*)(ab + aB + i * 2048 + sw1);
    }
#pragma unroll
    for (int j = 0; j < 2; ++j) {
      b0[j][0] = *(const bf16x8*)(ab + bB + j * 2048 + sw0);
      b0[j][1] = *(const bf16x8*)(ab + bB + j * 2048 + sw1);
    }
    if (t + 1 < T) STAGE_HALF((t + 1) & 1, R_AHI, Ahi_p, t + 1);
    LGKM(8);
    __builtin_amdgcn_s_barrier();
    LGKM(0);
    __builtin_amdgcn_s_setprio(1);
#pragma unroll
    for (int i = 0; i < 4; ++i)
#pragma unroll
      for (int j = 0; j < 2; ++j) {
        acc[i][j] = MFMA16(a[i][0], b0[j][0], acc[i][j]);
        acc[i][j] = MFMA16(a[i][1], b0[j][1], acc[i][j]);
      }
    __builtin_amdgcn_s_setprio(0);
    __builtin_amdgcn_s_barrier();

    // ---- ph1: Q2 = a(i0-3) x b(j2-3) ----  4 ds_read
#pragma unroll
    for (int j = 0; j < 2; ++j) {
      b1[j][0] = *(const bf16x8*)(ab + bB + (j + 2) * 2048 + sw0);
      b1[j][1] = *(const bf16x8*)(ab + bB + (j + 2) * 2048 + sw1);
    }
    __builtin_amdgcn_s_barrier();
    LGKM(0);
    __builtin_amdgcn_s_setprio(1);
#pragma unroll
    for (int i = 0; i < 4; ++i)
#pragma unroll
      for (int j = 0; j < 2; ++j) {
        acc[i][j + 2] = MFMA16(a[i][0], b1[j][0], acc[i][j + 2]);
        acc[i][j + 2] = MFMA16(a[i][1], b1[j][1], acc[i][j + 2]);
      }
    __builtin_amdgcn_s_setprio(0);
    __builtin_amdgcn_s_barrier();

    // ---- ph2: Q1 = a(i4-7) x b(j0-1) ----  8 ds_read + stage B-lo(t+2)
#pragma unroll
    for (int i = 0; i < 4; ++i) {
      a[i][0] = *(const bf16x8*)(ab + aB + (i + 4) * 2048 + sw0);
      a[i][1] = *(const bf16x8*)(ab + aB + (i + 4) * 2048 + sw1);
    }
    if (t + 2 < T) STAGE_HALF(t & 1, R_BLO, Blo_p, t + 2);
    __builtin_amdgcn_s_barrier();
    LGKM(0);
    __builtin_amdgcn_s_setprio(1);
#pragma unroll
    for (int i = 0; i < 4; ++i)
#pragma unroll
      for (int j = 0; j < 2; ++j) {
        acc[i + 4][j] = MFMA16(a[i][0], b0[j][0], acc[i + 4][j]);
        acc[i + 4][j] = MFMA16(a[i][1], b0[j][1], acc[i + 4][j]);
      }
    __builtin_amdgcn_s_setprio(0);
    __builtin_amdgcn_s_barrier();

    // ---- ph3: Q3 = a(i4-7) x b(j2-3) ----  stage A-lo/B-hi(t+2), per-K-tile vmcnt
    if (t + 2 < T) {
      STAGE_HALF(t & 1, R_ALO, Alo_p, t + 2);
      STAGE_HALF(t & 1, R_BHI, Bhi_p, t + 2);
      VMCNT(6);
    } else if (t + 1 < T) {
      VMCNT(0);
    }
    __builtin_amdgcn_s_barrier();
    __builtin_amdgcn_s_setprio(1);
#pragma unroll
    for (int i = 0; i < 4; ++i)
#pragma unroll
      for (int j = 0; j < 2; ++j) {
        acc[i + 4][j + 2] = MFMA16(a[i][0], b1[j][0], acc[i + 4][j + 2]);
        acc[i + 4][j + 2] = MFMA16(a[i][1], b1[j][1], acc[i + 4][j + 2]);
      }
    __builtin_amdgcn_s_setprio(0);
    __builtin_amdgcn_s_barrier();
  }
#undef STAGE_HALF

  // epilogue: C[row][col] = acc + bias[col]
#pragma unroll
  for (int j = 0; j < 4; ++j) {
    const int col = n0 + wn * 64 + j * 16 + fr;
    const float bv = bias[col];
#pragma unroll
    for (int i = 0; i < 8; ++i) {
      const int row0 = m0 + wm * 128 + i * 16 + hi * 4;
#pragma unroll
      for (int r = 0; r < 4; ++r)
        C[(size_t)(row0 + r) * N + col] = acc[i][j][r] + bv;
    }
  }
}

extern "C" void kernel_launch(void* const* d_in, const int* in_sizes, int n_in,
                              void* d_out, int out_size, void* d_ws, size_t ws_size,
                              hipStream_t stream) {
  const float* x = (const float*)d_in[0];     // [M,K]
  const float* w = (const float*)d_in[1];     // [N,K]
  const float* bias = (const float*)d_in[2];  // [N]
  float* out = (float*)d_out;

  const int MK = in_sizes[0];
  const int NK = in_sizes[1];
  const int N = in_sizes[2];
  const int K = NK / N;
  const int M = MK / K;

  __hip_bfloat16* qx = (__hip_bfloat16*)d_ws;
  __hip_bfloat16* qw = qx + (size_t)MK;

  const int gx = MK / 256;
  const int gtot = gx + NK / 256;
  qdq2<<<(gtot + 3) / 4, 256, 0, stream>>>(x, qx, gx, w, qw, gtot);

  hipFuncSetAttribute((const void*)gemm256, hipFuncAttributeMaxDynamicSharedMemorySize,
                      2 * BUF_BYTES);
  dim3 grid((M / BM) * (N / BN));
  gemm256<<<grid, dim3(THREADS), 2 * BUF_BYTES, stream>>>(qx, qw, bias, out, M, N, K);
}

// Round 5
// 101.307 us; speedup vs baseline: 1.1991x; 1.1991x over previous
//
#include <hip/hip_runtime.h>
#include <hip/hip_bf16.h>

typedef __attribute__((ext_vector_type(4))) int i32x4;
typedef __attribute__((ext_vector_type(4))) float f32x4;

#define BM 128
#define BN 128
#define BKB 64            // K-bytes per tile (64 i8 elems)
#define THREADS 256
#define TILE_BYTES 16384  // A 8KB + B 8KB
#define NBUF 4
#define SA_OFF 65536      // f32 sa[4][128]
#define SB_OFF 67584      // f32 sb[4][128]
#define LDS_TOTAL 69632

#define VMCNT(n) asm volatile("s_waitcnt vmcnt(" #n ")" ::: "memory")
#define MFMAI8(a, b, c) __builtin_amdgcn_mfma_i32_16x16x64_i8((a), (b), (c), 0, 0, 0)

static __device__ inline void gload_lds16(const void* g, void* l) {
  __builtin_amdgcn_global_load_lds((__attribute__((address_space(1))) void*)g,
                                   (__attribute__((address_space(3))) void*)l,
                                   16, 0, 0);
}

// ---------------- QDQ -> i8 {0,+-1,+-2} (=2q) + per-256-group f32 scale -------------
// reference: scale=max(absmax,1e-6); t=|x|/scale; q=0 (t<.25) / .5 (t<.75) / 1 ; exact.
__global__ __launch_bounds__(256) void qdq_i8(const float* __restrict__ x,
                                              signed char* __restrict__ qx,
                                              float* __restrict__ sax, int gx,
                                              const float* __restrict__ w,
                                              signed char* __restrict__ qw,
                                              float* __restrict__ sbx, int gtot) {
  int g = (blockIdx.x << 2) + (threadIdx.x >> 6);
  if (g >= gtot) return;
  const int lane = threadIdx.x & 63;
  const bool isx = (g < gx);
  const int gl = isx ? g : g - gx;
  const float* src = isx ? x : w;
  int* dst = (int*)(isx ? qx : qw);
  float* sc = isx ? sax : sbx;

  const size_t base = (size_t)gl * 256 + (size_t)lane * 4;
  float4 v = *reinterpret_cast<const float4*>(src + base);
  float amax = fmaxf(fmaxf(fabsf(v.x), fabsf(v.y)), fmaxf(fabsf(v.z), fabsf(v.w)));
#pragma unroll
  for (int off = 32; off > 0; off >>= 1)
    amax = fmaxf(amax, __shfl_xor(amax, off, 64));
  const float scale = fmaxf(amax, 1e-6f);
  const float inv = 1.0f / scale;  // compare-only use: t boundaries unaffected by rounding? use div to be exact
  float in[4] = {v.x, v.y, v.z, v.w};
  int packed = 0;
#pragma unroll
  for (int i = 0; i < 4; ++i) {
    float t = fabsf(in[i] / scale);                 // exact same op as reference
    int q2 = t < 0.25f ? 0 : (t < 0.75f ? 1 : 2);   // = 2*q
    if (in[i] < 0.0f) q2 = -q2;
    packed |= (q2 & 0xff) << (i * 8);
  }
  (void)inv;
  dst[(size_t)gl * 64 + lane] = packed;
  if (lane == 0) sc[gl] = scale;
}

// ---------------- GEMM i8: C = (2qA)(2qB)^T segmented i32, folded by sa*sb/4 --------
// 4 waves, wave-tile 64x64. LDS tile: A[128r][64B] @0, B[128r][64B] @8192.
// Pair-line swizzle (verified 0-conflict r3/r4): byte(r,c16) = (r>>1)*128 +
//   ((c + 4*(r&1)) ^ ((r>>1)&7))*16. gload_lds dest linear; SOURCE inverse-permuted.
__global__ __launch_bounds__(THREADS, 2) void gemm_i8(
    const signed char* __restrict__ A8,  // [M,K] i8
    const signed char* __restrict__ B8,  // [N,K] i8
    const float* __restrict__ sax,       // [M*4] group scales
    const float* __restrict__ sbx,       // [N*4]
    const float* __restrict__ bias,      // [N]
    float* __restrict__ C,               // [M,N] f32
    int M, int N, int K) {
  extern __shared__ char smem[];

  const int tid = threadIdx.x;
  const int lane = tid & 63;
  const int wid = tid >> 6;   // 0..3
  const int wm = wid >> 1;    // 0..1 -> 64-row strip
  const int wn = wid & 1;     // 0..1 -> 64-col strip
  const int fr = lane & 15;
  const int hi = lane >> 4;

  const int nwg = gridDim.x;
  int bid = blockIdx.x;
  if ((nwg & 7) == 0) bid = (bid & 7) * (nwg >> 3) + (bid >> 3);
  const int ntn = N / BN;
  const int tm = bid / ntn, tn = bid % ntn;
  const int m0 = tm * BM, n0 = tn * BN;

  // ---- scale staging: sa_lds[g][128], sb_lds[g][128] (transposed for b128 folds) ----
  float* sa_lds = (float*)(smem + SA_OFF);
  float* sb_lds = (float*)(smem + SB_OFF);
#pragma unroll
  for (int p = 0; p < 2; ++p) {
    int idx = p * 256 + tid;          // 0..511
    int row = idx & 127, g = idx >> 7;
    sa_lds[g * 128 + row] = sax[(size_t)(m0 + row) * 4 + g];
    sb_lds[g * 128 + row] = sbx[(size_t)(n0 + row) * 4 + g];
  }

  // ---- staging source map (inverse pair-line swizzle) ----
  // load l, thread tid: dest D=l*4096+tid*16 -> L=l*32+(tid>>3), S=tid&7
  // u = S^(L&7) = (tid&7)^((tid>>3)&7); r = l*64 + 2*(tid>>3) + (u>>2); c = u&3
  const int u = (tid & 7) ^ ((tid >> 3) & 7);
  const int r0 = 2 * (tid >> 3) + (u >> 2);
  const int cB = (u & 3) * 16;  // byte offset within row
  const size_t srcA = (size_t)(m0 + r0) * K + cB;
  const size_t srcB = (size_t)(n0 + r0) * K + cB;
  const size_t rowStep = (size_t)64 * K;
  const int d16 = tid * 16;

#define STAGE(bufi, tt) do {                                    \
    char* bb = smem + (size_t)(bufi) * TILE_BYTES;              \
    const signed char* ga = A8 + srcA + (size_t)(tt) * BKB;     \
    const signed char* gb = B8 + srcB + (size_t)(tt) * BKB;     \
    gload_lds16(ga,           bb + d16);                        \
    gload_lds16(ga + rowStep, bb + 4096 + d16);                 \
    gload_lds16(gb,           bb + 8192 + d16);                 \
    gload_lds16(gb + rowStep, bb + 12288 + d16);                \
  } while (0)

  // ---- swizzled read offsets: frag row = (wm|wn)*64 + i*16 + fr, chunk = hi ----
  const int slot16 = ((hi + 4 * (fr & 1)) ^ (fr >> 1)) << 4;
  const int aBase = (wm * 32 + (fr >> 1)) * 128 + slot16;         // + i*1024
  const int bBase = 8192 + (wn * 32 + (fr >> 1)) * 128 + slot16;  // + j*1024

  f32x4 master[4][4];
  i32x4 acc[4][4];
#pragma unroll
  for (int i = 0; i < 4; ++i)
#pragma unroll
    for (int j = 0; j < 4; ++j) {
      master[i][j] = (f32x4){0.f, 0.f, 0.f, 0.f};
      acc[i][j] = (i32x4){0, 0, 0, 0};
    }

  const int T = K / BKB;  // 16
  __syncthreads();        // scales visible; no loads in flight yet
  STAGE(0, 0);
  STAGE(1, 1);
  STAGE(2, 2);

  for (int t = 0; t < T; ++t) {
    if (t < T - 2) { VMCNT(8); } else if (t == T - 2) { VMCNT(4); } else { VMCNT(0); }
    __builtin_amdgcn_s_barrier();
    if (t + 3 < T) STAGE((t + 3) & 3, t + 3);  // overwrites buf[(t-1)&3]; its reads drained pre-barrier

    const char* ab = smem + (size_t)(t & 3) * TILE_BYTES;
    i32x4 a[4], b[4];
#pragma unroll
    for (int j = 0; j < 4; ++j) b[j] = *(const i32x4*)(ab + bBase + j * 1024);
#pragma unroll
    for (int i = 0; i < 4; ++i) a[i] = *(const i32x4*)(ab + aBase + i * 1024);

    __builtin_amdgcn_s_setprio(1);
#pragma unroll
    for (int i = 0; i < 4; ++i)
#pragma unroll
      for (int j = 0; j < 4; ++j)
        acc[i][j] = MFMAI8(a[i], b[j], acc[i][j]);
    __builtin_amdgcn_s_setprio(0);

    if ((t & 3) == 3) {  // segment fold: out += sa*sb/4 * acc ; exact i32 partials
      const int g = t >> 2;
      f32x4 sav[4];
      float sbq[4];
#pragma unroll
      for (int i = 0; i < 4; ++i)
        sav[i] = *(const f32x4*)(sa_lds + g * 128 + wm * 64 + i * 16 + hi * 4);
#pragma unroll
      for (int j = 0; j < 4; ++j)
        sbq[j] = sb_lds[g * 128 + wn * 64 + j * 16 + fr] * 0.25f;
#pragma unroll
      for (int i = 0; i < 4; ++i)
#pragma unroll
        for (int j = 0; j < 4; ++j) {
#pragma unroll
          for (int r = 0; r < 4; ++r)
            master[i][j][r] += (float)acc[i][j][r] * sav[i][r] * sbq[j];
          acc[i][j] = (i32x4){0, 0, 0, 0};
        }
    }
  }
#undef STAGE

  // epilogue: C[row][col] = master + bias[col]
#pragma unroll
  for (int j = 0; j < 4; ++j) {
    const int col = n0 + wn * 64 + j * 16 + fr;
    const float bv = bias[col];
#pragma unroll
    for (int i = 0; i < 4; ++i) {
      const int row0 = m0 + wm * 64 + i * 16 + hi * 4;
#pragma unroll
      for (int r = 0; r < 4; ++r)
        C[(size_t)(row0 + r) * N + col] = master[i][j][r] + bv;
    }
  }
}

extern "C" void kernel_launch(void* const* d_in, const int* in_sizes, int n_in,
                              void* d_out, int out_size, void* d_ws, size_t ws_size,
                              hipStream_t stream) {
  const float* x = (const float*)d_in[0];     // [M,K]
  const float* w = (const float*)d_in[1];     // [N,K]
  const float* bias = (const float*)d_in[2];  // [N]
  float* out = (float*)d_out;

  const int MK = in_sizes[0];
  const int NK = in_sizes[1];
  const int N = in_sizes[2];
  const int K = NK / N;
  const int M = MK / K;

  signed char* qx8 = (signed char*)d_ws;             // M*K
  signed char* qw8 = qx8 + (size_t)MK;               // N*K
  float* sax = (float*)(qw8 + (size_t)NK);           // MK/256
  float* sbx = sax + (size_t)(MK / 256);             // NK/256

  const int gx = MK / 256;
  const int gtot = gx + NK / 256;
  qdq_i8<<<(gtot + 3) / 4, 256, 0, stream>>>(x, qx8, sax, gx, w, qw8, sbx, gtot);

  hipFuncSetAttribute((const void*)gemm_i8, hipFuncAttributeMaxDynamicSharedMemorySize,
                      LDS_TOTAL);
  dim3 grid((M / BM) * (N / BN));
  gemm_i8<<<grid, dim3(THREADS), LDS_TOTAL, stream>>>(qx8, qw8, sax, sbx, bias, out,
                                                      M, N, K);
}